// Round 11
// baseline (2276.453 us; speedup 1.0000x reference)
//
#include <hip/hip_runtime.h>

// MipMap: out = relu(interp(G)+b1)@W2 + b2, G = sum_l b_l * blur_l(base@W1).
// Blur acts on spatial axes, W1 on the feature axis -> they commute; interp
// is linear over grid values. All compute fp32.
// History: R1-R8 never built/ran (zero-output signature). R9 (plain style)
// ran -> NaN = f32 inputs read as bf16. R10 finite 0.0864 = bf16 written
// into an f32 output buffer (packed-pair decode matches exactly; harness
// doc: output dtype follows the reference = float32). R11: all-f32 I/O,
// in_sizes-based pointer remap (sizes are unique), no host HIP API calls.

__global__ void kcoef(const float* blev, float* coef) {
    // coef[0..63] horiz taps, coef[64..127] vert taps * b_level, coef[128] b0
    if (blockIdx.x != 0 || threadIdx.x != 0) return;
    int offs[6];
    offs[0] = 0; offs[1] = 0; offs[2] = 2; offs[3] = 6; offs[4] = 14; offs[5] = 30;
    for (int l = 1; l <= 5; l++) {
        int s = 1 << l;
        int off = offs[l];
        float sum = 0.0f;
        for (int m = 0; m < s; m++) {
            float x = ((float)m - (float)(s - 1) * 0.5f) / ((float)s * 0.5f);
            float w = expf(-0.5f * x * x);
            coef[off + m] = w;
            sum += w;
        }
        float bl = blev[l];
        for (int m = 0; m < s; m++) {
            float w = coef[off + m] / sum;
            coef[off + m] = w;
            coef[64 + off + m] = w * bl;
        }
    }
    coef[128] = blev[0];
}

__global__ void kgemm(const float* base, const float* W1, int f0, int FC,
                      float* G0, int n) {
    int i = blockIdx.x * 256 + threadIdx.x;
    if (i >= n) return;
    int m = i / FC;
    int j = i - m * FC;
    float s = 0.0f;
    for (int k = 0; k < 128; k++)
        s += base[m * 128 + k] * W1[k * 128 + f0 + j];
    G0[i] = s;
}

__global__ void kinit(const float* G0, const float* coef, float* G, int n) {
    int i = blockIdx.x * 256 + threadIdx.x;
    if (i >= n) return;
    G[i] = coef[128] * G0[i];
}

__global__ void kblurH(const float* G0, const float* coef, float* T,
                       int FC, int s, int off, int n) {
    int i = blockIdx.x * 256 + threadIdx.x;
    if (i >= n) return;
    int f = i % FC;
    int r = i / FC;
    int x = r % 256;
    int y = r / 256;
    int h = s / 2;
    float a = 0.0f;
    for (int m = 0; m < s; m++) {
        int u = x + m - h;
        if (u < 0) u = -u;
        if (u > 255) u = 510 - u;
        a += coef[off + m] * G0[(y * 256 + u) * FC + f];
    }
    T[i] = a;
}

__global__ void kblurV(const float* T, const float* coef, float* G,
                       int FC, int s, int off, int n) {
    int i = blockIdx.x * 256 + threadIdx.x;
    if (i >= n) return;
    int f = i % FC;
    int r = i / FC;
    int x = r % 256;
    int y = r / 256;
    int h = s / 2;
    float a = 0.0f;
    for (int m = 0; m < s; m++) {
        int u = y + m - h;
        if (u < 0) u = -u;
        if (u > 255) u = 510 - u;
        a += coef[64 + off + m] * T[(u * 256 + x) * FC + f];
    }
    G[i] += a;
}

__global__ void kgather(const float* pt, const float* G, const float* b1,
                        const float* W2, int f0, int FC, float* accum,
                        int first) {
    int i = blockIdx.x * 256 + threadIdx.x;
    if (i >= 262144) return;
    float py = pt[2 * i];
    float px = pt[2 * i + 1];
    float ay = (py + 1.0f) * 0.5f * 255.0f;
    float ax = (px + 1.0f) * 0.5f * 255.0f;
    int iy = (int)ay;
    int ix = (int)ax;
    if (iy < 0) iy = 0;
    if (iy > 255) iy = 255;
    if (ix < 0) ix = 0;
    if (ix > 255) ix = 255;
    float fy = ay - (float)iy;
    float fx = ax - (float)ix;
    int iy1 = iy + 1; if (iy1 > 255) iy1 = 255;
    int ix1 = ix + 1; if (ix1 > 255) ix1 = 255;
    float w00 = (1.0f - fy) * (1.0f - fx);
    float w01 = (1.0f - fy) * fx;
    float w10 = fy * (1.0f - fx);
    float w11 = fy * fx;
    const float* r00 = G + (iy * 256 + ix) * FC;
    const float* r01 = G + (iy * 256 + ix1) * FC;
    const float* r10 = G + (iy1 * 256 + ix) * FC;
    const float* r11 = G + (iy1 * 256 + ix1) * FC;
    float o0 = 0.0f, o1 = 0.0f, o2 = 0.0f, o3 = 0.0f;
    for (int j = 0; j < FC; j++) {
        float v = w00 * r00[j] + w01 * r01[j] + w10 * r10[j] + w11 * r11[j];
        v += b1[f0 + j];
        if (v < 0.0f) v = 0.0f;
        o0 += v * W2[(f0 + j) * 4 + 0];
        o1 += v * W2[(f0 + j) * 4 + 1];
        o2 += v * W2[(f0 + j) * 4 + 2];
        o3 += v * W2[(f0 + j) * 4 + 3];
    }
    if (first) {
        accum[4 * i + 0] = o0;
        accum[4 * i + 1] = o1;
        accum[4 * i + 2] = o2;
        accum[4 * i + 3] = o3;
    } else {
        accum[4 * i + 0] += o0;
        accum[4 * i + 1] += o1;
        accum[4 * i + 2] += o2;
        accum[4 * i + 3] += o3;
    }
}

__global__ void kfinal(const float* accum, const float* b2, float* out) {
    int i = blockIdx.x * 256 + threadIdx.x;
    if (i >= 1048576) return;
    out[i] = accum[i] + b2[i & 3];
}

__global__ void kb2only(const float* b2, float* out) {
    int i = blockIdx.x * 256 + threadIdx.x;
    if (i >= 1048576) return;
    out[i] = b2[i & 3];
}

extern "C" void kernel_launch(void* const* d_in, const int* in_sizes, int n_in,
                              void* d_out, int out_size, void* d_ws, size_t ws_size,
                              hipStream_t stream) {
    // remap inputs by element count (all sizes unique); fallback positional
    const float* pt   = (const float*)d_in[0];
    const float* base = (const float*)d_in[1];
    const float* blev = (const float*)d_in[2];
    const float* W1   = (const float*)d_in[3];
    const float* b1   = (const float*)d_in[4];
    const float* W2   = (const float*)d_in[5];
    const float* b2   = (const float*)d_in[6];
    if (n_in == 7) {
        for (int i = 0; i < 7; i++) {
            int sz = in_sizes[i];
            if (sz == 524288)       pt   = (const float*)d_in[i];
            else if (sz == 8388608) base = (const float*)d_in[i];
            else if (sz == 6)       blev = (const float*)d_in[i];
            else if (sz == 16384)   W1   = (const float*)d_in[i];
            else if (sz == 128)     b1   = (const float*)d_in[i];
            else if (sz == 512)     W2   = (const float*)d_in[i];
            else if (sz == 4)       b2   = (const float*)d_in[i];
        }
    }
    float* out = (float*)d_out;
    char* ws = (char*)d_ws;

    // ws: coef 1024 B | accum 4 MiB f32 | G0 | T | G (f32, 65536*FC each)
    int FC = 0;
    for (int fc = 128; fc >= 1; fc /= 2) {
        size_t need = 1024 + 4194304 + 3 * (size_t)65536 * (size_t)fc * 4;
        if (ws_size >= need) { FC = fc; break; }
    }
    if (FC == 0) {
        kb2only<<<4096, 256, 0, stream>>>(b2, out);
        return;
    }

    float* coef  = (float*)ws;
    float* accum = (float*)(ws + 1024);
    float* G0 = (float*)(ws + 1024 + 4194304);
    float* T  = G0 + (size_t)65536 * FC;
    float* G  = T + (size_t)65536 * FC;

    kcoef<<<1, 64, 0, stream>>>(blev, coef);

    int n = 65536 * FC;
    int blocks = (n + 255) / 256;
    int svals[5]; int soffs[5];
    svals[0] = 2;  soffs[0] = 0;
    svals[1] = 4;  soffs[1] = 2;
    svals[2] = 8;  soffs[2] = 6;
    svals[3] = 16; soffs[3] = 14;
    svals[4] = 32; soffs[4] = 30;
    int nchunk = 128 / FC;
    for (int c = 0; c < nchunk; c++) {
        int f0 = c * FC;
        kgemm<<<blocks, 256, 0, stream>>>(base, W1, f0, FC, G0, n);
        kinit<<<blocks, 256, 0, stream>>>(G0, coef, G, n);
        for (int l = 0; l < 5; l++) {
            kblurH<<<blocks, 256, 0, stream>>>(G0, coef, T, FC, svals[l], soffs[l], n);
            kblurV<<<blocks, 256, 0, stream>>>(T, coef, G, FC, svals[l], soffs[l], n);
        }
        int first = 0;
        if (c == 0) first = 1;
        kgather<<<1024, 256, 0, stream>>>(pt, G, b1, W2, f0, FC, accum, first);
    }
    kfinal<<<4096, 256, 0, stream>>>(accum, b2, out);
}

// Round 12
// 648.273 us; speedup vs baseline: 3.5116x; 3.5116x over previous
//
#include <hip/hip_runtime.h>

// MipMap: out = relu(interp(G)+b1)@W2 + b2, G = sum_l b_l * blur_l(base@W1).
// Blur acts on spatial axes, W1 on the feature axis -> commute; interp linear.
// R11 PASSED (2276 us). Counters: kgather = 1261 us, 4.5 GB HBM fetch (8.4x
// over ideal 537 MB) -> per-thread 4 B walks thrash L1/L2 on random points.
// R12: (1) kgather -> wave-per-point, coalesced 512 B corner-row reads,
// shfl_xor reduce, writes out directly (+b2); (2) fused single-kernel blur
// (all 5 levels in a 63x63 LDS tile, 2 features/block, 50 KB LDS) replaces
// kinit + 10 global passes; (3) kgemm/kcoef unchanged (isolate their cost).
// ws known >= ~101 MB (FC=128 path ran in R11): need only coef + G0 + G.
// Style rules kept: no templates, no std headers, no unions (build safety).

__global__ void kcoef(const float* blev, float* coef) {
    // coef[0..63] horiz taps, coef[64..127] vert taps * b_level, coef[128] b0
    if (blockIdx.x != 0 || threadIdx.x != 0) return;
    int offs[6];
    offs[0] = 0; offs[1] = 0; offs[2] = 2; offs[3] = 6; offs[4] = 14; offs[5] = 30;
    for (int l = 1; l <= 5; l++) {
        int s = 1 << l;
        int off = offs[l];
        float sum = 0.0f;
        for (int m = 0; m < s; m++) {
            float x = ((float)m - (float)(s - 1) * 0.5f) / ((float)s * 0.5f);
            float w = expf(-0.5f * x * x);
            coef[off + m] = w;
            sum += w;
        }
        float bl = blev[l];
        for (int m = 0; m < s; m++) {
            float w = coef[off + m] / sum;
            coef[off + m] = w;
            coef[64 + off + m] = w * bl;
        }
    }
    coef[128] = blev[0];
}

__global__ void kgemm(const float* base, const float* W1, int f0, int FC,
                      float* G0, int n) {
    int i = blockIdx.x * 256 + threadIdx.x;
    if (i >= n) return;
    int m = i / FC;
    int j = i - m * FC;
    float s = 0.0f;
    for (int k = 0; k < 128; k++)
        s += base[m * 128 + k] * W1[k * 128 + f0 + j];
    G0[i] = s;
}

// one gaussian level: H pass (x) into H_t, V pass (y) accumulates into acc.
// in_t: [63][66 pad][2f] fp32; H_t: [63][33 pad][2f] fp32. 512 threads.
__device__ void blur_level(const float* in_t, float* H_t,
                           const float* kh_s, const float* kv_s,
                           int tid, float* acc, int S, int off) {
    int half = S / 2;
    int nrows = 31 + S;
    for (int g = tid; g < nrows * 8; g += 512) {
        int yy = (16 - half) + (g >> 3);
        int xg = g & 7;
        float a00 = 0.0f, a01 = 0.0f, a10 = 0.0f, a11 = 0.0f;
        float a20 = 0.0f, a21 = 0.0f, a30 = 0.0f, a31 = 0.0f;
        int cb = xg * 4 + 16 - half;
        for (int t = 0; t < S + 3; t++) {
            float v0 = in_t[(yy * 66 + cb + t) * 2 + 0];
            float v1 = in_t[(yy * 66 + cb + t) * 2 + 1];
            if (t < S)              { float k = kh_s[off + t];     a00 += k * v0; a01 += k * v1; }
            if (t >= 1 && t - 1 < S){ float k = kh_s[off + t - 1]; a10 += k * v0; a11 += k * v1; }
            if (t >= 2 && t - 2 < S){ float k = kh_s[off + t - 2]; a20 += k * v0; a21 += k * v1; }
            if (t >= 3 && t - 3 < S){ float k = kh_s[off + t - 3]; a30 += k * v0; a31 += k * v1; }
        }
        int hb = (yy * 33 + xg * 4) * 2;
        H_t[hb + 0] = a00; H_t[hb + 1] = a01;
        H_t[hb + 2] = a10; H_t[hb + 3] = a11;
        H_t[hb + 4] = a20; H_t[hb + 5] = a21;
        H_t[hb + 6] = a30; H_t[hb + 7] = a31;
    }
    __syncthreads();
    int xl = tid & 31;
    int ygrp = tid >> 5;
    int ybase = ygrp * 2 + 16 - half;
    for (int t = 0; t <= S; t++) {
        float h0 = H_t[((ybase + t) * 33 + xl) * 2 + 0];
        float h1 = H_t[((ybase + t) * 33 + xl) * 2 + 1];
        if (t < S)  { float k = kv_s[off + t];     acc[0] += k * h0; acc[1] += k * h1; }
        if (t >= 1) { float k = kv_s[off + t - 1]; acc[2] += k * h0; acc[3] += k * h1; }
    }
    __syncthreads();
}

// fused 6-level blur: 32x32 spatial tile x 2 features, halo 16 each side.
// grid(64, 8, 8): x = feature pair (fastest) so co-resident blocks share the
// 512 B-spaced cache lines of the f-inner layout.
__global__ void kblur(const float* G0, const float* coef, float* G) {
    __shared__ float in_t[63 * 66 * 2];
    __shared__ float H_t[63 * 33 * 2];
    __shared__ float kh_s[64];
    __shared__ float kv_s[64];
    __shared__ float b0s[1];
    int tid = threadIdx.x;
    int f0 = blockIdx.x * 2;
    int x0 = blockIdx.y * 32;
    int y0 = blockIdx.z * 32;
    if (tid < 64) { kh_s[tid] = coef[tid]; kv_s[tid] = coef[64 + tid]; }
    if (tid == 64) b0s[0] = coef[128];
    for (int i = tid; i < 63 * 63; i += 512) {
        int yy = i / 63;
        int xx = i - yy * 63;
        int gy = y0 + yy - 16; if (gy < 0) gy = -gy; if (gy > 255) gy = 510 - gy;
        int gx = x0 + xx - 16; if (gx < 0) gx = -gx; if (gx > 255) gx = 510 - gx;
        const float* src = G0 + (size_t)(gy * 256 + gx) * 128 + f0;
        in_t[(yy * 66 + xx) * 2 + 0] = src[0];
        in_t[(yy * 66 + xx) * 2 + 1] = src[1];
    }
    __syncthreads();
    int xl = tid & 31;
    int ygrp = tid >> 5;
    float acc[4];
    float b0 = b0s[0];
    acc[0] = b0 * in_t[((ygrp * 2 + 16) * 66 + xl + 16) * 2 + 0];
    acc[1] = b0 * in_t[((ygrp * 2 + 16) * 66 + xl + 16) * 2 + 1];
    acc[2] = b0 * in_t[((ygrp * 2 + 17) * 66 + xl + 16) * 2 + 0];
    acc[3] = b0 * in_t[((ygrp * 2 + 17) * 66 + xl + 16) * 2 + 1];
    blur_level(in_t, H_t, kh_s, kv_s, tid, acc, 2, 0);
    blur_level(in_t, H_t, kh_s, kv_s, tid, acc, 4, 2);
    blur_level(in_t, H_t, kh_s, kv_s, tid, acc, 8, 6);
    blur_level(in_t, H_t, kh_s, kv_s, tid, acc, 16, 14);
    blur_level(in_t, H_t, kh_s, kv_s, tid, acc, 32, 30);
    for (int i = 0; i < 2; i++) {
        int gy = y0 + ygrp * 2 + i;
        int gx = x0 + xl;
        float* dst = G + (size_t)(gy * 256 + gx) * 128 + f0;
        dst[0] = acc[i * 2 + 0];
        dst[1] = acc[i * 2 + 1];
    }
}

// wave-per-point gather: lane L owns features {2L, 2L+1}; corner rows are
// read as coalesced 512 B wave transactions; shfl_xor tree reduces 4 outputs.
__global__ void kgather(const float* pt, const float* G, const float* b1,
                        const float* W2, const float* b2, float* out) {
    int lane = threadIdx.x & 63;
    int wv = threadIdx.x >> 6;
    int i = blockIdx.x * 4 + wv;
    float py = pt[2 * i];
    float px = pt[2 * i + 1];
    float ay = (py + 1.0f) * 0.5f * 255.0f;
    float ax = (px + 1.0f) * 0.5f * 255.0f;
    int iy = (int)ay;
    int ix = (int)ax;
    if (iy < 0) iy = 0;
    if (iy > 255) iy = 255;
    if (ix < 0) ix = 0;
    if (ix > 255) ix = 255;
    float fy = ay - (float)iy;
    float fx = ax - (float)ix;
    int iy1 = iy + 1; if (iy1 > 255) iy1 = 255;
    int ix1 = ix + 1; if (ix1 > 255) ix1 = 255;
    float w00 = (1.0f - fy) * (1.0f - fx);
    float w01 = (1.0f - fy) * fx;
    float w10 = fy * (1.0f - fx);
    float w11 = fy * fx;
    int f = lane * 2;
    const float* r00 = G + (size_t)(iy * 256 + ix) * 128 + f;
    const float* r01 = G + (size_t)(iy * 256 + ix1) * 128 + f;
    const float* r10 = G + (size_t)(iy1 * 256 + ix) * 128 + f;
    const float* r11 = G + (size_t)(iy1 * 256 + ix1) * 128 + f;
    float v0 = w00 * r00[0] + w01 * r01[0] + w10 * r10[0] + w11 * r11[0] + b1[f];
    float v1 = w00 * r00[1] + w01 * r01[1] + w10 * r10[1] + w11 * r11[1] + b1[f + 1];
    if (v0 < 0.0f) v0 = 0.0f;
    if (v1 < 0.0f) v1 = 0.0f;
    float o0 = v0 * W2[f * 4 + 0] + v1 * W2[f * 4 + 4];
    float o1 = v0 * W2[f * 4 + 1] + v1 * W2[f * 4 + 5];
    float o2 = v0 * W2[f * 4 + 2] + v1 * W2[f * 4 + 6];
    float o3 = v0 * W2[f * 4 + 3] + v1 * W2[f * 4 + 7];
    for (int m = 32; m >= 1; m >>= 1) {
        o0 += __shfl_xor(o0, m);
        o1 += __shfl_xor(o1, m);
        o2 += __shfl_xor(o2, m);
        o3 += __shfl_xor(o3, m);
    }
    if (lane == 0) {
        out[4 * i + 0] = o0 + b2[0];
        out[4 * i + 1] = o1 + b2[1];
        out[4 * i + 2] = o2 + b2[2];
        out[4 * i + 3] = o3 + b2[3];
    }
}

extern "C" void kernel_launch(void* const* d_in, const int* in_sizes, int n_in,
                              void* d_out, int out_size, void* d_ws, size_t ws_size,
                              hipStream_t stream) {
    const float* pt   = (const float*)d_in[0];
    const float* base = (const float*)d_in[1];
    const float* blev = (const float*)d_in[2];
    const float* W1   = (const float*)d_in[3];
    const float* b1   = (const float*)d_in[4];
    const float* W2   = (const float*)d_in[5];
    const float* b2   = (const float*)d_in[6];
    if (n_in == 7) {
        for (int i = 0; i < 7; i++) {
            int sz = in_sizes[i];
            if (sz == 524288)       pt   = (const float*)d_in[i];
            else if (sz == 8388608) base = (const float*)d_in[i];
            else if (sz == 6)       blev = (const float*)d_in[i];
            else if (sz == 16384)   W1   = (const float*)d_in[i];
            else if (sz == 128)     b1   = (const float*)d_in[i];
            else if (sz == 512)     W2   = (const float*)d_in[i];
            else if (sz == 4)       b2   = (const float*)d_in[i];
        }
    }
    float* out = (float*)d_out;
    char* ws = (char*)d_ws;

    // ws: coef 1024 B | G0 32 MiB | G 32 MiB   (R11 proved ws >= ~101 MB)
    size_t need = 1024 + 2ull * 33554432ull;
    if (ws_size < need) return;

    float* coef = (float*)ws;
    float* G0 = (float*)(ws + 1024);
    float* G  = (float*)(ws + 1024 + 33554432);

    kcoef<<<1, 64, 0, stream>>>(blev, coef);
    kgemm<<<32768, 256, 0, stream>>>(base, W1, 0, 128, G0, 8388608);
    dim3 gb(64, 8, 8);
    kblur<<<gb, 512, 0, stream>>>(G0, coef, G);
    kgather<<<65536, 256, 0, stream>>>(pt, G, b1, W2, b2, out);
}

// Round 13
// 454.253 us; speedup vs baseline: 5.0114x; 1.4271x over previous
//
#include <hip/hip_runtime.h>

// MipMap: out = relu(interp(G)+b1)@W2 + b2, G = sum_l b_l * blur_l(base@W1).
// Blur acts on spatial axes, W1 on the feature axis -> commute; interp linear.
// R12 PASSED 648 us. kgemm = 260 us, VALUBusy 49%, MfmaUtil 0, HBM 2.4% ->
// scalar fp32 GEMM is VALU/issue bound at 16.5/157 TF. R13: kgemm -> bf16
// MFMA (16x16x32, guide-verified fragment layouts), inputs packed to bf16
// once (base) + W1 transposed to bf16 W1T (L1-resident B-frags). G0 stays
// f32; kblur/kgather byte-identical to R12. bf16 rounding budget ~3e-4.
// Style: no cstdint, no unions, no templates (R9's build-fix delta).

typedef short short8 __attribute__((ext_vector_type(8)));
typedef float f32x4 __attribute__((ext_vector_type(4)));

__device__ __forceinline__ unsigned short f2bfbits(float f) {
    unsigned int x = __float_as_uint(f);
    x += 0x7fffu + ((x >> 16) & 1u);   // round-to-nearest-even
    return (unsigned short)(x >> 16);
}

__global__ void kcoef(const float* blev, float* coef) {
    // coef[0..63] horiz taps, coef[64..127] vert taps * b_level, coef[128] b0
    if (blockIdx.x != 0 || threadIdx.x != 0) return;
    int offs[6];
    offs[0] = 0; offs[1] = 0; offs[2] = 2; offs[3] = 6; offs[4] = 14; offs[5] = 30;
    for (int l = 1; l <= 5; l++) {
        int s = 1 << l;
        int off = offs[l];
        float sum = 0.0f;
        for (int m = 0; m < s; m++) {
            float x = ((float)m - (float)(s - 1) * 0.5f) / ((float)s * 0.5f);
            float w = expf(-0.5f * x * x);
            coef[off + m] = w;
            sum += w;
        }
        float bl = blev[l];
        for (int m = 0; m < s; m++) {
            float w = coef[off + m] / sum;
            coef[off + m] = w;
            coef[64 + off + m] = w * bl;
        }
    }
    coef[128] = blev[0];
}

// pack base (f32, 8.4M) -> bf16, two elements per thread as one u32 store
__global__ void kconvA(const float* base, unsigned int* Abf2, int n2) {
    int i = blockIdx.x * 256 + threadIdx.x;
    if (i >= n2) return;
    unsigned int lo = f2bfbits(base[2 * i]);
    unsigned int hi = f2bfbits(base[2 * i + 1]);
    Abf2[i] = (hi << 16) | lo;
}

// W1 (k,n) f32 -> W1T (n,k) bf16 so B-fragments are contiguous 16 B loads
__global__ void kconvW(const float* W1, unsigned short* W1T) {
    int i = blockIdx.x * 256 + threadIdx.x;   // 16384
    int k = i >> 7;
    int n = i & 127;
    W1T[n * 128 + k] = f2bfbits(W1[i]);
}

// MFMA GEMM: G0(65536x128 f32) = base_bf16 @ W1_bf16. Wave = 16 rows x 128
// cols (8 tiles of 16x16, K-loop 4x32). Block = 4 waves = 64 rows.
// A-frag: A[m=lane&15][k=quad*8+j]; B-frag: B[k=quad*8+j][n=lane&15] (from
// W1T row n); D: row=quad*4+r, col=lane&15  (guide-verified m89/m91).
__global__ void kgemm(const unsigned short* Abf, const unsigned short* W1T,
                      float* G0) {
    int wv = threadIdx.x >> 6;
    int lane = threadIdx.x & 63;
    int row = lane & 15;
    int quad = lane >> 4;
    int m0 = blockIdx.x * 64 + wv * 16;
    f32x4 zero = {0.0f, 0.0f, 0.0f, 0.0f};
    f32x4 acc0 = zero; f32x4 acc1 = zero; f32x4 acc2 = zero; f32x4 acc3 = zero;
    f32x4 acc4 = zero; f32x4 acc5 = zero; f32x4 acc6 = zero; f32x4 acc7 = zero;
    for (int kc = 0; kc < 4; kc++) {
        int k0 = kc * 32 + quad * 8;
        short8 a = *(const short8*)(Abf + (size_t)(m0 + row) * 128 + k0);
        const unsigned short* wb = W1T + (size_t)row * 128 + k0;
        short8 b0 = *(const short8*)(wb + 0 * 16 * 128);
        short8 b1 = *(const short8*)(wb + 1 * 16 * 128);
        short8 b2 = *(const short8*)(wb + 2 * 16 * 128);
        short8 b3 = *(const short8*)(wb + 3 * 16 * 128);
        short8 b4 = *(const short8*)(wb + 4 * 16 * 128);
        short8 b5 = *(const short8*)(wb + 5 * 16 * 128);
        short8 b6 = *(const short8*)(wb + 6 * 16 * 128);
        short8 b7 = *(const short8*)(wb + 7 * 16 * 128);
        acc0 = __builtin_amdgcn_mfma_f32_16x16x32_bf16(a, b0, acc0, 0, 0, 0);
        acc1 = __builtin_amdgcn_mfma_f32_16x16x32_bf16(a, b1, acc1, 0, 0, 0);
        acc2 = __builtin_amdgcn_mfma_f32_16x16x32_bf16(a, b2, acc2, 0, 0, 0);
        acc3 = __builtin_amdgcn_mfma_f32_16x16x32_bf16(a, b3, acc3, 0, 0, 0);
        acc4 = __builtin_amdgcn_mfma_f32_16x16x32_bf16(a, b4, acc4, 0, 0, 0);
        acc5 = __builtin_amdgcn_mfma_f32_16x16x32_bf16(a, b5, acc5, 0, 0, 0);
        acc6 = __builtin_amdgcn_mfma_f32_16x16x32_bf16(a, b6, acc6, 0, 0, 0);
        acc7 = __builtin_amdgcn_mfma_f32_16x16x32_bf16(a, b7, acc7, 0, 0, 0);
    }
    float* gr = G0 + (size_t)(m0 + quad * 4) * 128 + row;
    for (int r = 0; r < 4; r++) {
        float* g = gr + (size_t)r * 128;
        g[0 * 16] = acc0[r]; g[1 * 16] = acc1[r];
        g[2 * 16] = acc2[r]; g[3 * 16] = acc3[r];
        g[4 * 16] = acc4[r]; g[5 * 16] = acc5[r];
        g[6 * 16] = acc6[r]; g[7 * 16] = acc7[r];
    }
}

// one gaussian level: H pass (x) into H_t, V pass (y) accumulates into acc.
__device__ void blur_level(const float* in_t, float* H_t,
                           const float* kh_s, const float* kv_s,
                           int tid, float* acc, int S, int off) {
    int half = S / 2;
    int nrows = 31 + S;
    for (int g = tid; g < nrows * 8; g += 512) {
        int yy = (16 - half) + (g >> 3);
        int xg = g & 7;
        float a00 = 0.0f, a01 = 0.0f, a10 = 0.0f, a11 = 0.0f;
        float a20 = 0.0f, a21 = 0.0f, a30 = 0.0f, a31 = 0.0f;
        int cb = xg * 4 + 16 - half;
        for (int t = 0; t < S + 3; t++) {
            float v0 = in_t[(yy * 66 + cb + t) * 2 + 0];
            float v1 = in_t[(yy * 66 + cb + t) * 2 + 1];
            if (t < S)              { float k = kh_s[off + t];     a00 += k * v0; a01 += k * v1; }
            if (t >= 1 && t - 1 < S){ float k = kh_s[off + t - 1]; a10 += k * v0; a11 += k * v1; }
            if (t >= 2 && t - 2 < S){ float k = kh_s[off + t - 2]; a20 += k * v0; a21 += k * v1; }
            if (t >= 3 && t - 3 < S){ float k = kh_s[off + t - 3]; a30 += k * v0; a31 += k * v1; }
        }
        int hb = (yy * 33 + xg * 4) * 2;
        H_t[hb + 0] = a00; H_t[hb + 1] = a01;
        H_t[hb + 2] = a10; H_t[hb + 3] = a11;
        H_t[hb + 4] = a20; H_t[hb + 5] = a21;
        H_t[hb + 6] = a30; H_t[hb + 7] = a31;
    }
    __syncthreads();
    int xl = tid & 31;
    int ygrp = tid >> 5;
    int ybase = ygrp * 2 + 16 - half;
    for (int t = 0; t <= S; t++) {
        float h0 = H_t[((ybase + t) * 33 + xl) * 2 + 0];
        float h1 = H_t[((ybase + t) * 33 + xl) * 2 + 1];
        if (t < S)  { float k = kv_s[off + t];     acc[0] += k * h0; acc[1] += k * h1; }
        if (t >= 1) { float k = kv_s[off + t - 1]; acc[2] += k * h0; acc[3] += k * h1; }
    }
    __syncthreads();
}

// fused 6-level blur: 32x32 spatial tile x 2 features, halo 16 each side.
__global__ void kblur(const float* G0, const float* coef, float* G) {
    __shared__ float in_t[63 * 66 * 2];
    __shared__ float H_t[63 * 33 * 2];
    __shared__ float kh_s[64];
    __shared__ float kv_s[64];
    __shared__ float b0s[1];
    int tid = threadIdx.x;
    int f0 = blockIdx.x * 2;
    int x0 = blockIdx.y * 32;
    int y0 = blockIdx.z * 32;
    if (tid < 64) { kh_s[tid] = coef[tid]; kv_s[tid] = coef[64 + tid]; }
    if (tid == 64) b0s[0] = coef[128];
    for (int i = tid; i < 63 * 63; i += 512) {
        int yy = i / 63;
        int xx = i - yy * 63;
        int gy = y0 + yy - 16; if (gy < 0) gy = -gy; if (gy > 255) gy = 510 - gy;
        int gx = x0 + xx - 16; if (gx < 0) gx = -gx; if (gx > 255) gx = 510 - gx;
        const float* src = G0 + (size_t)(gy * 256 + gx) * 128 + f0;
        in_t[(yy * 66 + xx) * 2 + 0] = src[0];
        in_t[(yy * 66 + xx) * 2 + 1] = src[1];
    }
    __syncthreads();
    int xl = tid & 31;
    int ygrp = tid >> 5;
    float acc[4];
    float b0 = b0s[0];
    acc[0] = b0 * in_t[((ygrp * 2 + 16) * 66 + xl + 16) * 2 + 0];
    acc[1] = b0 * in_t[((ygrp * 2 + 16) * 66 + xl + 16) * 2 + 1];
    acc[2] = b0 * in_t[((ygrp * 2 + 17) * 66 + xl + 16) * 2 + 0];
    acc[3] = b0 * in_t[((ygrp * 2 + 17) * 66 + xl + 16) * 2 + 1];
    blur_level(in_t, H_t, kh_s, kv_s, tid, acc, 2, 0);
    blur_level(in_t, H_t, kh_s, kv_s, tid, acc, 4, 2);
    blur_level(in_t, H_t, kh_s, kv_s, tid, acc, 8, 6);
    blur_level(in_t, H_t, kh_s, kv_s, tid, acc, 16, 14);
    blur_level(in_t, H_t, kh_s, kv_s, tid, acc, 32, 30);
    for (int i = 0; i < 2; i++) {
        int gy = y0 + ygrp * 2 + i;
        int gx = x0 + xl;
        float* dst = G + (size_t)(gy * 256 + gx) * 128 + f0;
        dst[0] = acc[i * 2 + 0];
        dst[1] = acc[i * 2 + 1];
    }
}

// wave-per-point gather: lane L owns features {2L, 2L+1}; coalesced 512 B
// corner-row reads; shfl_xor tree reduces 4 outputs; writes out (+b2).
__global__ void kgather(const float* pt, const float* G, const float* b1,
                        const float* W2, const float* b2, float* out) {
    int lane = threadIdx.x & 63;
    int wv = threadIdx.x >> 6;
    int i = blockIdx.x * 4 + wv;
    float py = pt[2 * i];
    float px = pt[2 * i + 1];
    float ay = (py + 1.0f) * 0.5f * 255.0f;
    float ax = (px + 1.0f) * 0.5f * 255.0f;
    int iy = (int)ay;
    int ix = (int)ax;
    if (iy < 0) iy = 0;
    if (iy > 255) iy = 255;
    if (ix < 0) ix = 0;
    if (ix > 255) ix = 255;
    float fy = ay - (float)iy;
    float fx = ax - (float)ix;
    int iy1 = iy + 1; if (iy1 > 255) iy1 = 255;
    int ix1 = ix + 1; if (ix1 > 255) ix1 = 255;
    float w00 = (1.0f - fy) * (1.0f - fx);
    float w01 = (1.0f - fy) * fx;
    float w10 = fy * (1.0f - fx);
    float w11 = fy * fx;
    int f = lane * 2;
    const float* r00 = G + (size_t)(iy * 256 + ix) * 128 + f;
    const float* r01 = G + (size_t)(iy * 256 + ix1) * 128 + f;
    const float* r10 = G + (size_t)(iy1 * 256 + ix) * 128 + f;
    const float* r11 = G + (size_t)(iy1 * 256 + ix1) * 128 + f;
    float v0 = w00 * r00[0] + w01 * r01[0] + w10 * r10[0] + w11 * r11[0] + b1[f];
    float v1 = w00 * r00[1] + w01 * r01[1] + w10 * r10[1] + w11 * r11[1] + b1[f + 1];
    if (v0 < 0.0f) v0 = 0.0f;
    if (v1 < 0.0f) v1 = 0.0f;
    float o0 = v0 * W2[f * 4 + 0] + v1 * W2[f * 4 + 4];
    float o1 = v0 * W2[f * 4 + 1] + v1 * W2[f * 4 + 5];
    float o2 = v0 * W2[f * 4 + 2] + v1 * W2[f * 4 + 6];
    float o3 = v0 * W2[f * 4 + 3] + v1 * W2[f * 4 + 7];
    for (int m = 32; m >= 1; m >>= 1) {
        o0 += __shfl_xor(o0, m);
        o1 += __shfl_xor(o1, m);
        o2 += __shfl_xor(o2, m);
        o3 += __shfl_xor(o3, m);
    }
    if (lane == 0) {
        out[4 * i + 0] = o0 + b2[0];
        out[4 * i + 1] = o1 + b2[1];
        out[4 * i + 2] = o2 + b2[2];
        out[4 * i + 3] = o3 + b2[3];
    }
}

extern "C" void kernel_launch(void* const* d_in, const int* in_sizes, int n_in,
                              void* d_out, int out_size, void* d_ws, size_t ws_size,
                              hipStream_t stream) {
    const float* pt   = (const float*)d_in[0];
    const float* base = (const float*)d_in[1];
    const float* blev = (const float*)d_in[2];
    const float* W1   = (const float*)d_in[3];
    const float* b1   = (const float*)d_in[4];
    const float* W2   = (const float*)d_in[5];
    const float* b2   = (const float*)d_in[6];
    if (n_in == 7) {
        for (int i = 0; i < 7; i++) {
            int sz = in_sizes[i];
            if (sz == 524288)       pt   = (const float*)d_in[i];
            else if (sz == 8388608) base = (const float*)d_in[i];
            else if (sz == 6)       blev = (const float*)d_in[i];
            else if (sz == 16384)   W1   = (const float*)d_in[i];
            else if (sz == 128)     b1   = (const float*)d_in[i];
            else if (sz == 512)     W2   = (const float*)d_in[i];
            else if (sz == 4)       b2   = (const float*)d_in[i];
        }
    }
    float* out = (float*)d_out;
    char* ws = (char*)d_ws;

    // ws: coef 1 KB | Abf 16 MiB bf16 | W1T 32 KB bf16 | G0 32 MiB | G 32 MiB
    size_t off0 = 1024;
    size_t off1 = off0 + 16777216;
    size_t off2 = off1 + 65536;
    size_t off3 = off2 + 33554432;
    size_t need = off3 + 33554432;
    if (ws_size < need) return;

    float* coef = (float*)ws;
    unsigned short* Abf = (unsigned short*)(ws + off0);
    unsigned short* W1T = (unsigned short*)(ws + off1);
    float* G0 = (float*)(ws + off2);
    float* G  = (float*)(ws + off3);

    kcoef<<<1, 64, 0, stream>>>(blev, coef);
    kconvA<<<16384, 256, 0, stream>>>(base, (unsigned int*)Abf, 4194304);
    kconvW<<<64, 256, 0, stream>>>(W1, W1T);
    kgemm<<<1024, 256, 0, stream>>>(Abf, W1T, G0);
    dim3 gb(64, 8, 8);
    kblur<<<gb, 512, 0, stream>>>(G0, coef, G);
    kgather<<<65536, 256, 0, stream>>>(pt, G, b1, W2, b2, out);
}